// Round 5
// baseline (61.254 us; speedup 1.0000x reference)
//
#include <hip/hip_runtime.h>

typedef float f32x4 __attribute__((ext_vector_type(4)));

// Problem dims (fixed by reference): bs=4, L=512, H=768, C=48
#define H_DIM 768
#define C_DIM 48
#define NROWS 2048          // bs * L
#define TWO_H 1536
#define WT_ELEMS (H_DIM * 96)   // 73728 floats

// ---------------------------------------------------------------------------
// Kernel 0: transpose W[48][1536] -> Wt[768][96] (k-major).
//   Wt[k][c] = W[c][k]        for c < 48   (i-half)
//   Wt[k][c] = W[c-48][768+k] for c >= 48  (j-half)
// Wt lives in the tail of d_out (bcast overwrites it afterwards).
// ---------------------------------------------------------------------------
__global__ __launch_bounds__(256) void wtrans_kernel(const float* __restrict__ W,
                                                     float* __restrict__ Wt) {
    const int idx = blockIdx.x * 256 + threadIdx.x;   // 0..18431
    const int c   = idx % 96;
    const int k   = (idx / 96) * 4;                   // 0..764
    const float* src = W + (size_t)(c % C_DIM) * TWO_H + (c / C_DIM) * H_DIM + k;
    const float4 v = *reinterpret_cast<const float4*>(src);
    Wt[(size_t)(k + 0) * 96 + c] = v.x;
    Wt[(size_t)(k + 1) * 96 + c] = v.y;
    Wt[(size_t)(k + 2) * 96 + c] = v.z;
    Wt[(size_t)(k + 3) * 96 + c] = v.w;
}

// ---------------------------------------------------------------------------
// Kernel 1 (v3): proj[half][row][c] = dot(hs[row,:], Wcol)
// grid = 512 blocks (4 rows each), block = 192 threads (3 waves) -> 2 blocks/CU.
// thread t: s = t%12 (owns cols 4s..4s+3 and 48+4s..48+4s+3),
//           r = (t/12)%4 (row), kg = t/48 (k-range of 192).
// Per 4-k step: 1 ds_read_b128 (hs) feeds 32 FMA; 8 f32x4 Wt loads with only
// 24 distinct addresses per wave (contiguous 192B runs, L2-resident).
// 4-way k-partials merged through 6KB LDS.
// ---------------------------------------------------------------------------
#define PR_ROWS 4
#define PR_KG   4
#define PR_KSEG 192

__global__ __launch_bounds__(192) void proj_kernel(const float* __restrict__ hs,
                                                   const float* __restrict__ Wt,
                                                   float* __restrict__ proj) {
    __shared__ float hs_lds[PR_ROWS][H_DIM + 4];       // +4 pad: r-rows on distinct banks
    __shared__ float part[PR_KG][12][PR_ROWS][8];      // 6 KB

    const int t    = threadIdx.x;
    const int s    = t % 12;
    const int r    = (t / 12) & 3;
    const int kg   = t / 48;                           // 0..3
    const int row0 = blockIdx.x * PR_ROWS;

    // Stage 4 hs rows (each row: 192 f32x4 = 192 threads, coalesced).
    {
        const f32x4* src = reinterpret_cast<const f32x4*>(hs + (size_t)row0 * H_DIM);
        #pragma unroll
        for (int rr = 0; rr < PR_ROWS; ++rr) {
            f32x4* dst = reinterpret_cast<f32x4*>(&hs_lds[rr][0]);
            dst[t] = src[rr * (H_DIM / 4) + t];
        }
    }
    __syncthreads();

    const f32x4* __restrict__ Wt4 = reinterpret_cast<const f32x4*>(Wt);

    float acc[8];
    #pragma unroll
    for (int e = 0; e < 8; ++e) acc[e] = 0.f;

    const int kbase = kg * PR_KSEG;
    for (int kk = 0; kk < PR_KSEG; kk += 4) {
        const int k = kbase + kk;
        const f32x4 h = *reinterpret_cast<const f32x4*>(&hs_lds[r][k]);
        #pragma unroll
        for (int j = 0; j < 4; ++j) {
            const f32x4 w0 = Wt4[(size_t)(k + j) * 24 + s];        // cols 4s..4s+3
            const f32x4 w1 = Wt4[(size_t)(k + j) * 24 + s + 12];   // cols 48+4s..
            const float hj = h[j];
            acc[0] += hj * w0.x;  acc[1] += hj * w0.y;
            acc[2] += hj * w0.z;  acc[3] += hj * w0.w;
            acc[4] += hj * w1.x;  acc[5] += hj * w1.y;
            acc[6] += hj * w1.z;  acc[7] += hj * w1.w;
        }
    }

    #pragma unroll
    for (int e = 0; e < 8; ++e) part[kg][s][r][e] = acc[e];
    __syncthreads();

    // Reduce 4 k-partials; 384 outputs, 2 per thread.
    #pragma unroll
    for (int o = t; o < PR_ROWS * 96; o += 192) {
        const int rr   = o / 96;
        const int c    = o % 96;
        const int half = c / 48;
        const int cl   = c % 48;
        float v = 0.f;
        #pragma unroll
        for (int g = 0; g < PR_KG; ++g)
            v += part[g][cl >> 2][rr][half * 4 + (cl & 3)];
        proj[(size_t)half * (NROWS * C_DIM) + (size_t)(row0 + rr) * C_DIM + cl] = v;
    }
}

// ---------------------------------------------------------------------------
// Kernel 2: out[b,i,j,c] = proj_i[b,i,c] + proj_j[b,j,c] + bias[c]
// grid = 2048 (one block per (b,i)), block = 256, 8 blocks/CU.
// proj_j slab (98 KB/batch) is L2-resident; plain stores (match fill-kernel
// behavior, which achieves 6.8 TB/s).
// ---------------------------------------------------------------------------
__global__ __launch_bounds__(256) void bcast_kernel(const float* __restrict__ proj,
                                                    const float* __restrict__ bias,
                                                    float* __restrict__ out) {
    const int gi = blockIdx.x;          // b*512 + i
    const int b  = gi >> 9;

    __shared__ f32x4 rowi[C_DIM / 4];   // proj_i[b,i,:] + bias  (12 f32x4)

    const int t = threadIdx.x;
    if (t < C_DIM / 4) {
        f32x4 pi = reinterpret_cast<const f32x4*>(proj + (size_t)gi * C_DIM)[t];
        f32x4 bb = reinterpret_cast<const f32x4*>(bias)[t];
        rowi[t] = pi + bb;
    }
    __syncthreads();

    const f32x4* __restrict__ pj =
        reinterpret_cast<const f32x4*>(proj + (size_t)NROWS * C_DIM
                                            + (size_t)b * 512 * C_DIM);
    f32x4* __restrict__ o =
        reinterpret_cast<f32x4*>(out) + (size_t)gi * (512 * C_DIM / 4);

    constexpr int SLAB_F4 = 512 * C_DIM / 4;   // 6144
    #pragma unroll
    for (int it = 0; it < SLAB_F4 / 256; ++it) {
        const int p  = it * 256 + t;
        const int c4 = p % 12;
        o[p] = pj[p] + rowi[c4];
    }
}

extern "C" void kernel_launch(void* const* d_in, const int* in_sizes, int n_in,
                              void* d_out, int out_size, void* d_ws, size_t ws_size,
                              hipStream_t stream) {
    const float* hs   = (const float*)d_in[0];   // (4, 512, 768) f32
    const float* W    = (const float*)d_in[1];   // (48, 1536)    f32
    const float* bias = (const float*)d_in[2];   // (48,)         f32
    float* out  = (float*)d_out;                 // (4,512,512,48) f32
    float* proj = (float*)d_ws;                  // 2*2048*48 floats = 786 KB

    // Wt lives in the tail of d_out; proj reads it before bcast overwrites it.
    float* Wt = out + (size_t)out_size - WT_ELEMS;

    wtrans_kernel<<<dim3(WT_ELEMS / 4 / 256), 256, 0, stream>>>(W, Wt);
    proj_kernel<<<dim3(NROWS / PR_ROWS), 192, 0, stream>>>(hs, Wt, proj);
    bcast_kernel<<<dim3(NROWS), 256, 0, stream>>>(proj, bias, out);
}